// Round 2
// baseline (111280.750 us; speedup 1.0000x reference)
//
#include <hip/hip_runtime.h>
#include <math.h>

// Recurrent 2-MLP network, B=65536 points, T=512 sequential steps.
// One thread per point; all intermediates in registers; weights read as
// wave-uniform (scalar) loads -> v_fmac with SGPR operand; fp32 throughout.

#define LOG2E 1.44269504088896340736f

__device__ __forceinline__ float lrelu(float z) {
    // leaky_relu with slope 0.01: max(z, 0.01z) works for both signs.
    return fmaxf(z, 0.01f * z);
}

__device__ __forceinline__ float sigmoidf_fast(float z) {
    // sigmoid(z) = 1 / (1 + e^{-z}) = 1 / (1 + 2^{-z*log2e})
    float p = __builtin_amdgcn_exp2f(-LOG2E * z);
    return __builtin_amdgcn_rcpf(1.0f + p);
}

__global__ void __launch_bounds__(256, 1)
recnet_kernel(const float* __restrict__ w,
              const float* __restrict__ Wh1, const float* __restrict__ bh1,
              const float* __restrict__ Wh2, const float* __restrict__ bh2,
              const float* __restrict__ Wh3, const float* __restrict__ bh3,
              const float* __restrict__ Wx1, const float* __restrict__ bx1,
              const float* __restrict__ Wx2, const float* __restrict__ bx2,
              const float* __restrict__ Wx3, const float* __restrict__ bx3,
              float* __restrict__ out, int B, int T)
{
    const int b = blockIdx.x * blockDim.x + threadIdx.x;
    if (b >= B) return;

    float h0 = w[2 * b + 0];
    float h1 = w[2 * b + 1];

    float* __restrict__ orow = out + (size_t)b * (size_t)T * 2;

    for (int t = 0; t < T; ++t) {
        // ---- h = lrelu(h @ Wh1 + bh1) : 2 -> 50 ----
        float a1[50];
#pragma unroll
        for (int j = 0; j < 50; ++j) {
            float z = fmaf(h1, Wh1[50 + j], bh1[j]);
            z = fmaf(h0, Wh1[j], z);
            a1[j] = lrelu(z);
        }

        // ---- h = lrelu(h @ Wh2 + bh2) : 50 -> 20 ----
        float a2[20];
#pragma unroll
        for (int j = 0; j < 20; ++j) {
            float z = bh2[j];
#pragma unroll
            for (int k = 0; k < 50; ++k) {
                z = fmaf(a1[k], Wh2[k * 20 + j], z);
            }
            a2[j] = lrelu(z);
        }

        // ---- h = lrelu(h @ Wh3 + bh3) : 20 -> 2 ----
        {
            float z0 = bh3[0];
            float z1 = bh3[1];
#pragma unroll
            for (int k = 0; k < 20; ++k) {
                z0 = fmaf(a2[k], Wh3[2 * k + 0], z0);
                z1 = fmaf(a2[k], Wh3[2 * k + 1], z1);
            }
            h0 = lrelu(z0);
            h1 = lrelu(z1);
        }

        // ---- x = sigmoid(h @ Wx1 + bx1) : 2 -> 50 ----
        float x1[50];
#pragma unroll
        for (int j = 0; j < 50; ++j) {
            float z = fmaf(h1, Wx1[50 + j], bx1[j]);
            z = fmaf(h0, Wx1[j], z);
            x1[j] = sigmoidf_fast(z);
        }

        // ---- x = sigmoid(x @ Wx2 + bx2) : 50 -> 20 ----
        float x2[20];
#pragma unroll
        for (int j = 0; j < 20; ++j) {
            float z = bx2[j];
#pragma unroll
            for (int k = 0; k < 50; ++k) {
                z = fmaf(x1[k], Wx2[k * 20 + j], z);
            }
            x2[j] = sigmoidf_fast(z);
        }

        // ---- x = sigmoid(x @ Wx3 + bx3) : 20 -> 2 ----
        float z0 = bx3[0];
        float z1 = bx3[1];
#pragma unroll
        for (int k = 0; k < 20; ++k) {
            z0 = fmaf(x2[k], Wx3[2 * k + 0], z0);
            z1 = fmaf(x2[k], Wx3[2 * k + 1], z1);
        }
        float xo0 = sigmoidf_fast(z0);
        float xo1 = sigmoidf_fast(z1);

        // out[b][t][0:2] — 8B store; partial lines merge in L2 across t.
        reinterpret_cast<float2*>(orow)[t] = make_float2(xo0, xo1);
    }
}

extern "C" void kernel_launch(void* const* d_in, const int* in_sizes, int n_in,
                              void* d_out, int out_size, void* d_ws, size_t ws_size,
                              hipStream_t stream)
{
    const float* w   = (const float*)d_in[0];
    const float* bh1 = (const float*)d_in[2];
    const float* Wh1 = (const float*)d_in[1];
    const float* Wh2 = (const float*)d_in[3];
    const float* bh2 = (const float*)d_in[4];
    const float* Wh3 = (const float*)d_in[5];
    const float* bh3 = (const float*)d_in[6];
    const float* Wx1 = (const float*)d_in[7];
    const float* bx1 = (const float*)d_in[8];
    const float* Wx2 = (const float*)d_in[9];
    const float* bx2 = (const float*)d_in[10];
    const float* Wx3 = (const float*)d_in[11];
    const float* bx3 = (const float*)d_in[12];

    const int B = in_sizes[0] / 2;           // 65536
    const int T = out_size / (B * 2);        // 512

    float* out = (float*)d_out;

    const int block = 256;
    const int grid  = (B + block - 1) / block;

    recnet_kernel<<<grid, block, 0, stream>>>(
        w, Wh1, bh1, Wh2, bh2, Wh3, bh3,
        Wx1, bx1, Wx2, bx2, Wx3, bx3,
        out, B, T);
}

// Round 6
// 9295.307 us; speedup vs baseline: 11.9717x; 11.9717x over previous
//
#include <hip/hip_runtime.h>

#define LOG2E 1.44269504088896340736f

__device__ __forceinline__ float lrelu(float z) { return fmaxf(z, 0.01f * z); }
__device__ __forceinline__ float sigf(float z) {
    // sigmoid(z) = 1 / (1 + 2^(-z*log2e))
    float p = __builtin_amdgcn_exp2f(-LOG2E * z);
    return __builtin_amdgcn_rcpf(1.0f + p);
}

// =================== Phase 1: recurrent h-path ===================
// One thread per point. h_{t+1} = lrelu3(h_t); stores h_t into out[b][t]
// (phase 2 rewrites the same slot in place with x_t = G(h_t)).
// Weights in LDS (uniform ds_read_b128 broadcasts); biases in VGPRs.
__global__ void __launch_bounds__(256, 1)
hpath_kernel(const float* __restrict__ w,
             const float* __restrict__ Wh1, const float* __restrict__ bh1,
             const float* __restrict__ Wh2, const float* __restrict__ bh2,
             const float* __restrict__ Wh3, const float* __restrict__ bh3,
             float2* __restrict__ out, int B, int T)
{
    __shared__ float4 sW1a[13], sW1b[13];  // Wh1 rows [2][50] padded to 52
    __shared__ float4 sW2[250];            // Wh2 [50][20], row k at sW2[5k..5k+4]
    __shared__ float4 sW3[10];             // Wh3 [20][2], p -> rows 2p,2p+1
    {
        const int tid = threadIdx.x;
        float* a = (float*)sW1a;
        float* b = (float*)sW1b;
        if (tid < 52) {
            a[tid] = (tid < 50) ? Wh1[tid]      : 0.f;
            b[tid] = (tid < 50) ? Wh1[50 + tid] : 0.f;
        }
        float* s2 = (float*)sW2;
        for (int i = tid; i < 1000; i += 256) s2[i] = Wh2[i];
        float* s3 = (float*)sW3;
        if (tid < 40) s3[tid] = Wh3[tid];
    }
    __syncthreads();

    // Biases -> registers (occupancy is grid-pinned at 1 wave/SIMD; VGPRs free)
    float rb1[52], rb2[20];
#pragma unroll
    for (int j = 0; j < 52; ++j) rb1[j] = (j < 50) ? bh1[j] : 0.f;
#pragma unroll
    for (int j = 0; j < 20; ++j) rb2[j] = bh2[j];
    const float rb3x = bh3[0], rb3y = bh3[1];

    const int bidx = blockIdx.x * blockDim.x + threadIdx.x;
    if (bidx >= B) return;
    float h0 = w[2 * bidx], h1 = w[2 * bidx + 1];
    float2* __restrict__ orow = out + (size_t)bidx * (size_t)T;

    for (int t = 0; t < T; ++t) {
        // ---- 2 -> 50 (padded 52), lrelu ----
        float a1[52];
#pragma unroll
        for (int q = 0; q < 13; ++q) {
            float4 va = sW1a[q], vb = sW1b[q];
            a1[4*q+0] = lrelu(fmaf(h1, vb.x, fmaf(h0, va.x, rb1[4*q+0])));
            a1[4*q+1] = lrelu(fmaf(h1, vb.y, fmaf(h0, va.y, rb1[4*q+1])));
            a1[4*q+2] = lrelu(fmaf(h1, vb.z, fmaf(h0, va.z, rb1[4*q+2])));
            a1[4*q+3] = lrelu(fmaf(h1, vb.w, fmaf(h0, va.w, rb1[4*q+3])));
        }
        // ---- 50 -> 20, lrelu ----
        float z[20];
#pragma unroll
        for (int j = 0; j < 20; ++j) z[j] = rb2[j];
#pragma unroll
        for (int k = 0; k < 50; ++k) {
            const float ak = a1[k];
#pragma unroll
            for (int c = 0; c < 5; ++c) {
                float4 v = sW2[k*5 + c];
                z[4*c+0] = fmaf(ak, v.x, z[4*c+0]);
                z[4*c+1] = fmaf(ak, v.y, z[4*c+1]);
                z[4*c+2] = fmaf(ak, v.z, z[4*c+2]);
                z[4*c+3] = fmaf(ak, v.w, z[4*c+3]);
            }
        }
        float a2[20];
#pragma unroll
        for (int j = 0; j < 20; ++j) a2[j] = lrelu(z[j]);
        // ---- 20 -> 2, lrelu ----
        float z0 = rb3x, z1 = rb3y;
#pragma unroll
        for (int p = 0; p < 10; ++p) {
            float4 v = sW3[p];  // (W[2p][0], W[2p][1], W[2p+1][0], W[2p+1][1])
            z0 = fmaf(a2[2*p+0], v.x, z0);
            z1 = fmaf(a2[2*p+0], v.y, z1);
            z0 = fmaf(a2[2*p+1], v.z, z0);
            z1 = fmaf(a2[2*p+1], v.w, z1);
        }
        h0 = lrelu(z0); h1 = lrelu(z1);
        orow[t] = make_float2(h0, h1);
    }
}

// =================== Phase 2: x = G(h), in place ===================
// Grid-stride over NP = B*T independent points; flat index == out index.
// Fully coalesced read+write; weights/biases from LDS broadcasts.
__global__ void __launch_bounds__(256)
xpath_kernel(const float* __restrict__ Wx1, const float* __restrict__ bx1,
             const float* __restrict__ Wx2, const float* __restrict__ bx2,
             const float* __restrict__ Wx3, const float* __restrict__ bx3,
             float2* __restrict__ out, int NP)
{
    __shared__ float4 sW1a[13], sW1b[13], sB1[13];
    __shared__ float4 sW2[250], sB2[5];
    __shared__ float4 sW3[10];
    __shared__ float2 sB3;
    {
        const int tid = threadIdx.x;
        float* a  = (float*)sW1a;
        float* b  = (float*)sW1b;
        float* b1 = (float*)sB1;
        if (tid < 52) {
            a[tid]  = (tid < 50) ? Wx1[tid]      : 0.f;
            b[tid]  = (tid < 50) ? Wx1[50 + tid] : 0.f;
            b1[tid] = (tid < 50) ? bx1[tid]      : 0.f;
        }
        float* s2 = (float*)sW2;
        for (int i = tid; i < 1000; i += 256) s2[i] = Wx2[i];
        float* b2 = (float*)sB2;
        if (tid < 20) b2[tid] = bx2[tid];
        float* s3 = (float*)sW3;
        if (tid < 40) s3[tid] = Wx3[tid];
        if (tid == 0) sB3 = make_float2(bx3[0], bx3[1]);
    }
    __syncthreads();

    const int stride = gridDim.x * blockDim.x;
    for (int i = blockIdx.x * blockDim.x + threadIdx.x; i < NP; i += stride) {
        const float2 h = out[i];
        const float h0 = h.x, h1 = h.y;

        // ---- 2 -> 50 (padded 52), sigmoid ----
        float x1[52];
#pragma unroll
        for (int q = 0; q < 13; ++q) {
            float4 va = sW1a[q], vb = sW1b[q], bb = sB1[q];
            x1[4*q+0] = sigf(fmaf(h1, vb.x, fmaf(h0, va.x, bb.x)));
            x1[4*q+1] = sigf(fmaf(h1, vb.y, fmaf(h0, va.y, bb.y)));
            x1[4*q+2] = sigf(fmaf(h1, vb.z, fmaf(h0, va.z, bb.z)));
            x1[4*q+3] = sigf(fmaf(h1, vb.w, fmaf(h0, va.w, bb.w)));
        }
        // ---- 50 -> 20, sigmoid ----
        float4 zv[5];
#pragma unroll
        for (int c = 0; c < 5; ++c) zv[c] = sB2[c];
#pragma unroll
        for (int k = 0; k < 50; ++k) {
            const float xk = x1[k];
#pragma unroll
            for (int c = 0; c < 5; ++c) {
                float4 v = sW2[k*5 + c];
                zv[c].x = fmaf(xk, v.x, zv[c].x);
                zv[c].y = fmaf(xk, v.y, zv[c].y);
                zv[c].z = fmaf(xk, v.z, zv[c].z);
                zv[c].w = fmaf(xk, v.w, zv[c].w);
            }
        }
        float x2[20];
#pragma unroll
        for (int c = 0; c < 5; ++c) {
            x2[4*c+0] = sigf(zv[c].x);
            x2[4*c+1] = sigf(zv[c].y);
            x2[4*c+2] = sigf(zv[c].z);
            x2[4*c+3] = sigf(zv[c].w);
        }
        // ---- 20 -> 2, sigmoid ----
        float2 b3 = sB3;
        float z0 = b3.x, z1 = b3.y;
#pragma unroll
        for (int p = 0; p < 10; ++p) {
            float4 v = sW3[p];
            z0 = fmaf(x2[2*p+0], v.x, z0);
            z1 = fmaf(x2[2*p+0], v.y, z1);
            z0 = fmaf(x2[2*p+1], v.z, z0);
            z1 = fmaf(x2[2*p+1], v.w, z1);
        }
        out[i] = make_float2(sigf(z0), sigf(z1));
    }
}

extern "C" void kernel_launch(void* const* d_in, const int* in_sizes, int n_in,
                              void* d_out, int out_size, void* d_ws, size_t ws_size,
                              hipStream_t stream)
{
    const float* w   = (const float*)d_in[0];
    const float* Wh1 = (const float*)d_in[1];
    const float* bh1 = (const float*)d_in[2];
    const float* Wh2 = (const float*)d_in[3];
    const float* bh2 = (const float*)d_in[4];
    const float* Wh3 = (const float*)d_in[5];
    const float* bh3 = (const float*)d_in[6];
    const float* Wx1 = (const float*)d_in[7];
    const float* bx1 = (const float*)d_in[8];
    const float* Wx2 = (const float*)d_in[9];
    const float* bx2 = (const float*)d_in[10];
    const float* Wx3 = (const float*)d_in[11];
    const float* bx3 = (const float*)d_in[12];

    const int B  = in_sizes[0] / 2;        // 65536
    const int T  = out_size / (B * 2);     // 512
    const int NP = B * T;                  // 33.5M independent (b,t) points

    float2* out2 = (float2*)d_out;

    // Phase 1: recurrent h-path, one thread per point.
    hpath_kernel<<<(B + 255) / 256, 256, 0, stream>>>(
        w, Wh1, bh1, Wh2, bh2, Wh3, bh3, out2, B, T);

    // Phase 2: independent x-path over all (b,t), in place on d_out.
    const int blocks2 = 16384;  // grid-stride; ~8 iters/thread, LDS staged once
    xpath_kernel<<<blocks2, 256, 0, stream>>>(
        Wx1, bx1, Wx2, bx2, Wx3, bx3, out2, NP);
}

// Round 10
// 4703.209 us; speedup vs baseline: 23.6606x; 1.9764x over previous
//
#include <hip/hip_runtime.h>

#define LOG2E 1.44269504088896340736f

__device__ __forceinline__ float lrelu(float z) { return fmaxf(z, 0.01f * z); }
__device__ __forceinline__ float sigf(float z) {
    // sigmoid(z) = 1 / (1 + 2^(-z*log2e))
    float p = __builtin_amdgcn_exp2f(-LOG2E * z);
    return __builtin_amdgcn_rcpf(1.0f + p);
}

// Broadcast weight element (i) from the lane-distributed register file.
// (i) must be a compile-time constant after unrolling: reg = i>>6, lane = i&63.
// v_readlane_b32 -> SGPR, consumed as the scalar operand of v_fma. No memory.
#define WQ(i) __int_as_float(__builtin_amdgcn_readlane(__float_as_int(wreg[(i) >> 6]), (i) & 63))

// =================== Phase 1: recurrent h-path ===================
// B threads = 1024 waves = 1 wave/SIMD (grid-pinned). The t-loop touches NO
// memory except the h-store: all 1212 weights live distributed across the
// wave's lanes (19 VGPRs/lane) and are broadcast via v_readlane. This removes
// the per-CU-shared LDS pipe from the critical path entirely (it was ~14K
// cyc/step serialized across the CU's 4 waves).
// Packing order: W1[2][50] (0..99), b1 (100..149), W2[50][20] row-major
// (150..1149), b2 (1150..1169), W3[20][2] (1170..1209), b3 (1210..1211).
__global__ void __launch_bounds__(256, 1)
hpath_kernel(const float* __restrict__ w,
             const float* __restrict__ Wh1, const float* __restrict__ bh1,
             const float* __restrict__ Wh2, const float* __restrict__ bh2,
             const float* __restrict__ Wh3, const float* __restrict__ bh3,
             float2* __restrict__ out, int B, int T)
{
    const int lane = threadIdx.x & 63;

    float wreg[19];
#pragma unroll
    for (int r = 0; r < 19; ++r) {
        const int idx = r * 64 + lane;
        float v = 0.f;
        if      (idx < 100)  v = Wh1[idx];
        else if (idx < 150)  v = bh1[idx - 100];
        else if (idx < 1150) v = Wh2[idx - 150];
        else if (idx < 1170) v = bh2[idx - 1150];
        else if (idx < 1210) v = Wh3[idx - 1170];
        else if (idx < 1212) v = bh3[idx - 1210];
        wreg[r] = v;
    }

    const int bidx = blockIdx.x * blockDim.x + threadIdx.x;
    if (bidx >= B) return;   // B % 256 == 0, never taken; wreg loaded above anyway

    float h0 = w[2 * bidx], h1 = w[2 * bidx + 1];
    float2* __restrict__ orow = out + (size_t)bidx * (size_t)T;

    for (int t = 0; t < T; ++t) {
        // ---- 2 -> 50, lrelu ----
        float a1[50];
#pragma unroll
        for (int j = 0; j < 50; ++j)
            a1[j] = lrelu(fmaf(h0, WQ(j), fmaf(h1, WQ(50 + j), WQ(100 + j))));

        // ---- 50 -> 20 (pre-activation in acc) ----
        float acc[20];
#pragma unroll
        for (int c = 0; c < 20; ++c) acc[c] = WQ(1150 + c);
#pragma unroll
        for (int k = 0; k < 50; ++k) {
            const float ak = a1[k];
#pragma unroll
            for (int c = 0; c < 20; ++c)
                acc[c] = fmaf(ak, WQ(150 + k * 20 + c), acc[c]);
        }

        // ---- 20 -> 2, lrelu (activation fused into the dot) ----
        float z0 = WQ(1210), z1 = WQ(1211);
#pragma unroll
        for (int k = 0; k < 20; ++k) {
            const float a2k = lrelu(acc[k]);
            z0 = fmaf(a2k, WQ(1170 + 2 * k + 0), z0);
            z1 = fmaf(a2k, WQ(1170 + 2 * k + 1), z1);
        }
        h0 = lrelu(z0); h1 = lrelu(z1);
        orow[t] = make_float2(h0, h1);
    }
}

// =================== Phase 2: x = G(h), in place, 4 points/thread ===========
// Amortizes the uniform LDS broadcast reads 4x (310 b128 per 4 points).
// Layer 1 is fused into the layer-2 accumulation (no x1[50] array).
// float4 loads/stores; flat group index == out index (in place on d_out).
__global__ void __launch_bounds__(256)
xpath_kernel(const float* __restrict__ Wx1, const float* __restrict__ bx1,
             const float* __restrict__ Wx2, const float* __restrict__ bx2,
             const float* __restrict__ Wx3, const float* __restrict__ bx3,
             float2* __restrict__ out, int NG)   // NG = NP/4 four-point groups
{
    __shared__ float4 sL1[50];   // (W1[0][k], W1[1][k], b1[k], 0)
    __shared__ float4 sW2[250];  // W2[50][20] row-major; row k at [5k..5k+4]
    __shared__ float4 sW3[10];   // (W3[2q][0], W3[2q][1], W3[2q+1][0], W3[2q+1][1])
    __shared__ float4 sB2[5];
    __shared__ float2 sB3;
    {
        const int tid = threadIdx.x;
        if (tid < 50) sL1[tid] = make_float4(Wx1[tid], Wx1[50 + tid], bx1[tid], 0.f);
        float* s2 = (float*)sW2;
        for (int i = tid; i < 1000; i += 256) s2[i] = Wx2[i];
        if (tid < 40) ((float*)sW3)[tid] = Wx3[tid];
        if (tid < 20) ((float*)sB2)[tid] = bx2[tid];
        if (tid == 0) sB3 = make_float2(bx3[0], bx3[1]);
    }
    __syncthreads();

    const int stride = gridDim.x * blockDim.x;
    for (int g = blockIdx.x * blockDim.x + threadIdx.x; g < NG; g += stride) {
        const float4 hv01 = reinterpret_cast<const float4*>(out)[2 * g];
        const float4 hv23 = reinterpret_cast<const float4*>(out)[2 * g + 1];
        const float h0[4] = {hv01.x, hv01.z, hv23.x, hv23.z};
        const float h1[4] = {hv01.y, hv01.w, hv23.y, hv23.w};

        float acc[4][20];
#pragma unroll
        for (int c4 = 0; c4 < 5; ++c4) {
            const float4 b = sB2[c4];
#pragma unroll
            for (int p = 0; p < 4; ++p) {
                acc[p][4 * c4 + 0] = b.x; acc[p][4 * c4 + 1] = b.y;
                acc[p][4 * c4 + 2] = b.z; acc[p][4 * c4 + 3] = b.w;
            }
        }
        // layers 1+2 fused over k
#pragma unroll
        for (int k = 0; k < 50; ++k) {
            const float4 l1 = sL1[k];
            float xk[4];
#pragma unroll
            for (int p = 0; p < 4; ++p)
                xk[p] = sigf(fmaf(h0[p], l1.x, fmaf(h1[p], l1.y, l1.z)));
#pragma unroll
            for (int c4 = 0; c4 < 5; ++c4) {
                const float4 v = sW2[k * 5 + c4];
#pragma unroll
                for (int p = 0; p < 4; ++p) {
                    acc[p][4 * c4 + 0] = fmaf(xk[p], v.x, acc[p][4 * c4 + 0]);
                    acc[p][4 * c4 + 1] = fmaf(xk[p], v.y, acc[p][4 * c4 + 1]);
                    acc[p][4 * c4 + 2] = fmaf(xk[p], v.z, acc[p][4 * c4 + 2]);
                    acc[p][4 * c4 + 3] = fmaf(xk[p], v.w, acc[p][4 * c4 + 3]);
                }
            }
        }
        // layer 3 (sigmoid of acc fused into the dot)
        const float2 b3 = sB3;
        float z0[4], z1[4];
#pragma unroll
        for (int p = 0; p < 4; ++p) { z0[p] = b3.x; z1[p] = b3.y; }
#pragma unroll
        for (int q = 0; q < 10; ++q) {
            const float4 v = sW3[q];
#pragma unroll
            for (int p = 0; p < 4; ++p) {
                const float x2a = sigf(acc[p][2 * q + 0]);
                const float x2b = sigf(acc[p][2 * q + 1]);
                z0[p] = fmaf(x2a, v.x, z0[p]); z1[p] = fmaf(x2a, v.y, z1[p]);
                z0[p] = fmaf(x2b, v.z, z0[p]); z1[p] = fmaf(x2b, v.w, z1[p]);
            }
        }
        const float4 o01 = make_float4(sigf(z0[0]), sigf(z1[0]), sigf(z0[1]), sigf(z1[1]));
        const float4 o23 = make_float4(sigf(z0[2]), sigf(z1[2]), sigf(z0[3]), sigf(z1[3]));
        reinterpret_cast<float4*>(out)[2 * g]     = o01;
        reinterpret_cast<float4*>(out)[2 * g + 1] = o23;
    }
}

extern "C" void kernel_launch(void* const* d_in, const int* in_sizes, int n_in,
                              void* d_out, int out_size, void* d_ws, size_t ws_size,
                              hipStream_t stream)
{
    const float* w   = (const float*)d_in[0];
    const float* Wh1 = (const float*)d_in[1];
    const float* bh1 = (const float*)d_in[2];
    const float* Wh2 = (const float*)d_in[3];
    const float* bh2 = (const float*)d_in[4];
    const float* Wh3 = (const float*)d_in[5];
    const float* bh3 = (const float*)d_in[6];
    const float* Wx1 = (const float*)d_in[7];
    const float* bx1 = (const float*)d_in[8];
    const float* Wx2 = (const float*)d_in[9];
    const float* bx2 = (const float*)d_in[10];
    const float* Wx3 = (const float*)d_in[11];
    const float* bx3 = (const float*)d_in[12];

    const int B  = in_sizes[0] / 2;        // 65536
    const int T  = out_size / (B * 2);     // 512
    const int NP = B * T;                  // 33.5M (b,t) points; divisible by 4
    const int NG = NP / 4;

    float2* out2 = (float2*)d_out;

    // Phase 1: recurrent h-path (readlane-distributed weights, no LDS).
    hpath_kernel<<<(B + 255) / 256, 256, 0, stream>>>(
        w, Wh1, bh1, Wh2, bh2, Wh3, bh3, out2, B, T);

    // Phase 2: x = G(h) in place, 4 points/thread.
    xpath_kernel<<<4096, 256, 0, stream>>>(
        Wx1, bx1, Wx2, bx2, Wx3, bx3, out2, NG);
}

// Round 11
// 4397.154 us; speedup vs baseline: 25.3074x; 1.0696x over previous
//
#include <hip/hip_runtime.h>

#define LOG2E 1.44269504088896340736f

__device__ __forceinline__ float lrelu(float z) { return fmaxf(z, 0.01f * z); }
__device__ __forceinline__ float sigf(float z) {
    // sigmoid(z) = 1 / (1 + 2^(-z*log2e))
    float p = __builtin_amdgcn_exp2f(-LOG2E * z);
    return __builtin_amdgcn_rcpf(1.0f + p);
}

// Broadcast weight element (i) from the lane-distributed register file.
// (i) must be a compile-time constant after unrolling: reg = i>>6, lane = i&63.
#define WQ(i) __int_as_float(__builtin_amdgcn_readlane(__float_as_int(wreg[(i) >> 6]), (i) & 63))

// =================== Phase 1: recurrent h-path ===================
// R10 evidence: pure-readlane version hit VALUBusy 92% (VALU-issue-bound,
// 12.4K cyc/step) with the LDS pipe idle. Split the weight broadcasts:
//   - W2 rows 0..17 (360 floats, 90 float4) via LDS uniform ds_read_b128
//     (costs LDS-pipe cycles, ~0 VALU),
//   - remaining 852 weights lane-distributed + v_readlane (costs VALU).
// Balanced so VALU ~ (1290+852)*2 ~ 4.3K cyc/step and LDS-pipe
// ~ 4*90*12 ~ 4.3K cyc/CU/step. No barrier in t-loop -> waves desync.
// wreg packing (852 floats, 14 VGPRs/lane):
//   0..99 W1 | 100..149 b1 | 150..789 W2 rows 18..49 | 790..809 b2
//   | 810..849 W3 | 850..851 b3
__global__ void __launch_bounds__(256, 1)
hpath_kernel(const float* __restrict__ w,
             const float* __restrict__ Wh1, const float* __restrict__ bh1,
             const float* __restrict__ Wh2, const float* __restrict__ bh2,
             const float* __restrict__ Wh3, const float* __restrict__ bh3,
             float2* __restrict__ out, int B, int T)
{
    __shared__ float4 sW2[90];   // W2 rows 0..17, row k at [5k..5k+4]
    {
        float* s2 = (float*)sW2;
        for (int i = threadIdx.x; i < 360; i += 256) s2[i] = Wh2[i];
    }

    const int lane = threadIdx.x & 63;
    float wreg[14];
#pragma unroll
    for (int r = 0; r < 14; ++r) {
        const int idx = r * 64 + lane;
        float v = 0.f;
        if      (idx < 100) v = Wh1[idx];
        else if (idx < 150) v = bh1[idx - 100];
        else if (idx < 790) v = Wh2[360 + (idx - 150)];   // rows 18..49
        else if (idx < 810) v = bh2[idx - 790];
        else if (idx < 850) v = Wh3[idx - 810];
        else if (idx < 852) v = bh3[idx - 850];
        wreg[r] = v;
    }
    __syncthreads();

    const int bidx = blockIdx.x * blockDim.x + threadIdx.x;
    if (bidx >= B) return;   // B % 256 == 0: never taken

    float h0 = w[2 * bidx], h1 = w[2 * bidx + 1];
    float2* __restrict__ orow = out + (size_t)bidx * (size_t)T;

    for (int t = 0; t < T; ++t) {
        // ---- 2 -> 50, lrelu (weights via readlane) ----
        float a1[50];
#pragma unroll
        for (int j = 0; j < 50; ++j)
            a1[j] = lrelu(fmaf(h0, WQ(j), fmaf(h1, WQ(50 + j), WQ(100 + j))));

        // ---- 50 -> 20 accumulate ----
        float acc[20];
#pragma unroll
        for (int c = 0; c < 20; ++c) acc[c] = WQ(790 + c);

        // rows 0..17 from LDS (ds_read_b128 broadcast; compiler hoists the
        // loads up so they overlap the W1 VALU work above)
#pragma unroll
        for (int k = 0; k < 18; ++k) {
            const float ak = a1[k];
#pragma unroll
            for (int c = 0; c < 5; ++c) {
                const float4 v = sW2[k * 5 + c];
                acc[4*c+0] = fmaf(ak, v.x, acc[4*c+0]);
                acc[4*c+1] = fmaf(ak, v.y, acc[4*c+1]);
                acc[4*c+2] = fmaf(ak, v.z, acc[4*c+2]);
                acc[4*c+3] = fmaf(ak, v.w, acc[4*c+3]);
            }
        }
        // rows 18..49 via readlane
#pragma unroll
        for (int k = 18; k < 50; ++k) {
            const float ak = a1[k];
#pragma unroll
            for (int c = 0; c < 20; ++c)
                acc[c] = fmaf(ak, WQ(150 + (k - 18) * 20 + c), acc[c]);
        }

        // ---- 20 -> 2, lrelu (activation fused into the dot) ----
        float z0 = WQ(850), z1 = WQ(851);
#pragma unroll
        for (int k = 0; k < 20; ++k) {
            const float a2k = lrelu(acc[k]);
            z0 = fmaf(a2k, WQ(810 + 2 * k + 0), z0);
            z1 = fmaf(a2k, WQ(810 + 2 * k + 1), z1);
        }
        h0 = lrelu(z0); h1 = lrelu(z1);
        orow[t] = make_float2(h0, h1);
    }
}

// =================== Phase 2: x = G(h), in place, 4 points/thread ===========
// (unchanged from R6 — awaiting its own counters now that hpath < xpath)
__global__ void __launch_bounds__(256)
xpath_kernel(const float* __restrict__ Wx1, const float* __restrict__ bx1,
             const float* __restrict__ Wx2, const float* __restrict__ bx2,
             const float* __restrict__ Wx3, const float* __restrict__ bx3,
             float2* __restrict__ out, int NG)   // NG = NP/4 four-point groups
{
    __shared__ float4 sL1[50];   // (W1[0][k], W1[1][k], b1[k], 0)
    __shared__ float4 sW2[250];  // W2[50][20] row-major; row k at [5k..5k+4]
    __shared__ float4 sW3[10];   // (W3[2q][0], W3[2q][1], W3[2q+1][0], W3[2q+1][1])
    __shared__ float4 sB2[5];
    __shared__ float2 sB3;
    {
        const int tid = threadIdx.x;
        if (tid < 50) sL1[tid] = make_float4(Wx1[tid], Wx1[50 + tid], bx1[tid], 0.f);
        float* s2 = (float*)sW2;
        for (int i = tid; i < 1000; i += 256) s2[i] = Wx2[i];
        if (tid < 40) ((float*)sW3)[tid] = Wx3[tid];
        if (tid < 20) ((float*)sB2)[tid] = bx2[tid];
        if (tid == 0) sB3 = make_float2(bx3[0], bx3[1]);
    }
    __syncthreads();

    const int stride = gridDim.x * blockDim.x;
    for (int g = blockIdx.x * blockDim.x + threadIdx.x; g < NG; g += stride) {
        const float4 hv01 = reinterpret_cast<const float4*>(out)[2 * g];
        const float4 hv23 = reinterpret_cast<const float4*>(out)[2 * g + 1];
        const float h0[4] = {hv01.x, hv01.z, hv23.x, hv23.z};
        const float h1[4] = {hv01.y, hv01.w, hv23.y, hv23.w};

        float acc[4][20];
#pragma unroll
        for (int c4 = 0; c4 < 5; ++c4) {
            const float4 b = sB2[c4];
#pragma unroll
            for (int p = 0; p < 4; ++p) {
                acc[p][4 * c4 + 0] = b.x; acc[p][4 * c4 + 1] = b.y;
                acc[p][4 * c4 + 2] = b.z; acc[p][4 * c4 + 3] = b.w;
            }
        }
        // layers 1+2 fused over k
#pragma unroll
        for (int k = 0; k < 50; ++k) {
            const float4 l1 = sL1[k];
            float xk[4];
#pragma unroll
            for (int p = 0; p < 4; ++p)
                xk[p] = sigf(fmaf(h0[p], l1.x, fmaf(h1[p], l1.y, l1.z)));
#pragma unroll
            for (int c4 = 0; c4 < 5; ++c4) {
                const float4 v = sW2[k * 5 + c4];
#pragma unroll
                for (int p = 0; p < 4; ++p) {
                    acc[p][4 * c4 + 0] = fmaf(xk[p], v.x, acc[p][4 * c4 + 0]);
                    acc[p][4 * c4 + 1] = fmaf(xk[p], v.y, acc[p][4 * c4 + 1]);
                    acc[p][4 * c4 + 2] = fmaf(xk[p], v.z, acc[p][4 * c4 + 2]);
                    acc[p][4 * c4 + 3] = fmaf(xk[p], v.w, acc[p][4 * c4 + 3]);
                }
            }
        }
        // layer 3 (sigmoid of acc fused into the dot)
        const float2 b3 = sB3;
        float z0[4], z1[4];
#pragma unroll
        for (int p = 0; p < 4; ++p) { z0[p] = b3.x; z1[p] = b3.y; }
#pragma unroll
        for (int q = 0; q < 10; ++q) {
            const float4 v = sW3[q];
#pragma unroll
            for (int p = 0; p < 4; ++p) {
                const float x2a = sigf(acc[p][2 * q + 0]);
                const float x2b = sigf(acc[p][2 * q + 1]);
                z0[p] = fmaf(x2a, v.x, z0[p]); z1[p] = fmaf(x2a, v.y, z1[p]);
                z0[p] = fmaf(x2b, v.z, z0[p]); z1[p] = fmaf(x2b, v.w, z1[p]);
            }
        }
        const float4 o01 = make_float4(sigf(z0[0]), sigf(z1[0]), sigf(z0[1]), sigf(z1[1]));
        const float4 o23 = make_float4(sigf(z0[2]), sigf(z1[2]), sigf(z0[3]), sigf(z1[3]));
        reinterpret_cast<float4*>(out)[2 * g]     = o01;
        reinterpret_cast<float4*>(out)[2 * g + 1] = o23;
    }
}

extern "C" void kernel_launch(void* const* d_in, const int* in_sizes, int n_in,
                              void* d_out, int out_size, void* d_ws, size_t ws_size,
                              hipStream_t stream)
{
    const float* w   = (const float*)d_in[0];
    const float* Wh1 = (const float*)d_in[1];
    const float* bh1 = (const float*)d_in[2];
    const float* Wh2 = (const float*)d_in[3];
    const float* bh2 = (const float*)d_in[4];
    const float* Wh3 = (const float*)d_in[5];
    const float* bh3 = (const float*)d_in[6];
    const float* Wx1 = (const float*)d_in[7];
    const float* bx1 = (const float*)d_in[8];
    const float* Wx2 = (const float*)d_in[9];
    const float* bx2 = (const float*)d_in[10];
    const float* Wx3 = (const float*)d_in[11];
    const float* bx3 = (const float*)d_in[12];

    const int B  = in_sizes[0] / 2;        // 65536
    const int T  = out_size / (B * 2);     // 512
    const int NP = B * T;                  // 33.5M (b,t) points; divisible by 4
    const int NG = NP / 4;

    float2* out2 = (float2*)d_out;

    // Phase 1: recurrent h-path (split LDS/readlane weight broadcasts).
    hpath_kernel<<<(B + 255) / 256, 256, 0, stream>>>(
        w, Wh1, bh1, Wh2, bh2, Wh3, bh3, out2, B, T);

    // Phase 2: x = G(h) in place, 4 points/thread.
    xpath_kernel<<<4096, 256, 0, stream>>>(
        Wx1, bx1, Wx2, bx2, Wx3, bx3, out2, NG);
}